// Round 8
// baseline (247.501 us; speedup 1.0000x reference)
//
#include <hip/hip_runtime.h>
#include <hip/hip_bf16.h>

// RotaryMultiHeadAttention on MI355X (gfx950)
// B=2, S=2048, E=1024, H=16, Dh=64
//
// Pipeline (4 launches):
//   prep:        conv_x + transpose_w + rope_table fused (flat grid, 3 ranges)
//   gemm_qkv:    fused proj + RoPE; K,V in MFMA-fragment order; coalesced
//                epilogue via per-wave LDS strips
//   flash_attn:  barrier-free K-loop, exp2 softmax, psum-via-ones-MFMA
//   gemm_bt_f32: d_out = attn @ Wo^T fp32 (overwrites rope table)

typedef unsigned short u16;
typedef unsigned int u32;
typedef __attribute__((ext_vector_type(8))) short short8;   // 8 bf16 (4 VGPRs)
typedef __attribute__((ext_vector_type(4))) float f32x4;    // MFMA C/D

#define MFMA16(a, b, c) __builtin_amdgcn_mfma_f32_16x16x32_bf16((a), (b), (c), 0, 0, 0)

typedef __attribute__((address_space(3))) u16 lds_u16;
typedef __attribute__((address_space(1))) const u16 glb_u16;

#define QSCALE 0.18033688011f   // 0.125 * log2(e): flash uses exp2

__device__ __forceinline__ void gload16(const u16* g, u16* l) {
    __builtin_amdgcn_global_load_lds((glb_u16*)g, (lds_u16*)l, 16, 0, 0);
}

__device__ __forceinline__ u16 f2bf(float f) {
    __hip_bfloat16 h = __float2bfloat16(f);
    return *reinterpret_cast<u16*>(&h);
}

// pack two fp32 -> two bf16 (round-half-up; ±1/2 ulp vs RNE, fine for P)
__device__ __forceinline__ u32 pk2(float a, float b) {
    u32 ua = __float_as_uint(a) + 0x8000u;
    u32 ub = __float_as_uint(b) + 0x8000u;
    return (ua >> 16) | (ub & 0xffff0000u);
}

// ---------------- fused prep: conv_x | transpose_w | rope_table --------------
__global__ __launch_bounds__(256) void prep(const float* __restrict__ q,
                                            const float* __restrict__ k,
                                            const float* __restrict__ v,
                                            const float* __restrict__ w0,
                                            const float* __restrict__ w1,
                                            const float* __restrict__ w2,
                                            const float* __restrict__ w3,
                                            u16* __restrict__ X3,
                                            u16* __restrict__ WT,
                                            float2* __restrict__ tab) {
    __shared__ float t[32][33];
    int blk = blockIdx.x, tid = threadIdx.x;
    if (blk < 12288) {
        // fp32 -> bf16 conversion of q/k/v
        int z = blk >> 12, xb = blk & 4095;
        const float* src = (z == 0) ? q : (z == 1) ? k : v;
        int i = (xb * 256 + tid) * 4;
        float4 f = *reinterpret_cast<const float4*>(src + i);
        ushort4 o;
        o.x = f2bf(f.x); o.y = f2bf(f.y); o.z = f2bf(f.z); o.w = f2bf(f.w);
        *reinterpret_cast<ushort4*>(X3 + (size_t)z * 4194304 + i) = o;
    } else if (blk < 16384) {
        // weight transpose + bf16: WT[z][n][k] = W[k][n]
        int idx = blk - 12288;
        int zc = idx & 3;
        int n0 = ((idx >> 2) & 31) * 32, k0 = (idx >> 7) * 32;
        const float* Ws[4] = {w0, w1, w2, w3};
        const float* W = Ws[zc];
        int tx = tid & 31, ty = tid >> 5;
        for (int r = 0; r < 4; r++)
            t[ty + r * 8][tx] = W[(k0 + ty + r * 8) * 1024 + n0 + tx];
        __syncthreads();
        u16* out = WT + (size_t)zc * 1048576;
        for (int r = 0; r < 4; r++)
            out[(n0 + ty + r * 8) * 1024 + k0 + tx] = f2bf(t[tx][ty + r * 8]);
    } else {
        // rope table: tab[s][d] = (cos, sin)(s * 10000^(-d/32))
        int gid = (blk - 16384) * 256 + tid;
        int s = gid >> 5, d = gid & 31;
        float inv = powf(10000.f, -(float)d / 32.f);  // accurate; phase matters at s~2048
        float fr = (float)s * inv;
        tab[gid] = make_float2(cosf(fr), sinf(fr));
    }
}

// ---------------- fused QKV GEMM + RoPE + fragment-order pack ----------------
// Kf element (bh, srel, d): t=srel>>4, lf=srel&15, kk=d>>5, qd=(d>>3)&3, j=d&7
//   addr = bh*131072 + ((t*2+kk)*4+qd)*128 + lf*8 + j
// Vf element (bh, srel, d): u=srel>>5, qv=(srel>>3)&3, j0=srel&7, dt=d>>4, lf=d&15
//   addr = bh*131072 + ((u*4+dt)*4+qv)*128 + lf*8 + j0
// Q/K epilogue: rope in registers -> per-wave LDS strip [16][72] -> coalesced
// 16B/lane stores. NOTE: one i-tile strip = 16x64 = 1024 u16 = 2 KB; a wave
// reads 1 KB per short8 pass, so BOTH paths need TWO readback passes (R7 bug:
// Q did one pass -> half of Q's columns were never written).
__global__ __launch_bounds__(256) void gemm_qkv(const u16* __restrict__ Aall,
                                                const u16* __restrict__ WT,
                                                u16* __restrict__ Qp,
                                                u16* __restrict__ Kf,
                                                u16* __restrict__ Vf,
                                                const float2* __restrict__ tab) {
    int z = blockIdx.z;
    const u16* A  = Aall + (size_t)z * 4194304;
    const u16* Bt = WT + (size_t)z * 1048576;
    const int K = 1024;
    int m0 = blockIdx.y * 128, n0 = blockIdx.x * 128;
    __shared__ u16 smem[9216];   // As[4096] | Bs[4096]; epilogue strips reuse (4x2304)
    u16* As = smem;
    u16* Bs = smem + 4096;
    int tid = threadIdx.x;
    int wave = tid >> 6, lane = tid & 63, quad = lane >> 4, l16 = lane & 15;
    int wm = (wave >> 1) * 64, wn = (wave & 1) * 64;
    f32x4 acc[4][4];
    for (int i = 0; i < 4; i++)
        for (int j = 0; j < 4; j++)
            for (int r = 0; r < 4; r++) acc[i][j][r] = 0.f;

    for (int k0 = 0; k0 < K; k0 += 32) {
        __syncthreads();
        for (int c = 0; c < 2; c++) {
            int e = (tid + c * 256) * 8;
            int row = e >> 5, col = e & 31;
            gload16(&A[(size_t)(m0 + row) * K + k0 + col], &As[e]);
            gload16(&Bt[(size_t)(n0 + row) * K + k0 + col], &Bs[e]);
        }
        __syncthreads();
        short8 af[4], bfr[4];
        for (int i = 0; i < 4; i++)
            af[i] = *reinterpret_cast<const short8*>(&As[(wm + i * 16 + l16) * 32 + quad * 8]);
        for (int j = 0; j < 4; j++)
            bfr[j] = *reinterpret_cast<const short8*>(&Bs[(wn + j * 16 + l16) * 32 + quad * 8]);
        for (int i = 0; i < 4; i++)
            for (int j = 0; j < 4; j++)
                acc[i][j] = MFMA16(af[i], bfr[j], acc[i][j]);
    }

    int h = (n0 + wn) >> 6;                  // head index of this wave's 64-col strip
    if (z == 2) {
        // V -> fragment order, r-packed ushort4 stores (no LDS use)
        for (int i = 0; i < 4; i++) {
            int sbase = m0 + wm + i * 16 + quad * 4;
            int b = sbase >> 11, srel = sbase & 2047;
            int u = srel >> 5, qv = (srel >> 3) & 3, j0 = srel & 7;
            u16* Vbh = Vf + ((size_t)(b * 16 + h)) * 131072;
            for (int j = 0; j < 4; j++) {
                ushort4 o;
                o.x = f2bf(acc[i][j][0]);
                o.y = f2bf(acc[i][j][1]);
                o.z = f2bf(acc[i][j][2]);
                o.w = f2bf(acc[i][j][3]);
                *reinterpret_cast<ushort4*>(
                    &Vbh[(size_t)(((u * 4 + j) * 4 + qv) * 128 + l16 * 8 + j0)]) = o;
            }
        }
    } else {
        __syncthreads();                       // done reading As/Bs
        u16* strip = smem + wave * 2304;       // per-wave [16][72]
        const float qs = (z == 0) ? QSCALE : 1.f;
        for (int i = 0; i < 4; i++) {
            int mb = m0 + wm + i * 16;
            int b = mb >> 11, srel0 = mb & 2047;
            // rope in registers, write rotated rows into strip (C-layout order)
            for (int r = 0; r < 4; r++) {
                int srel = srel0 + quad * 4 + r;
                for (int j2 = 0; j2 < 2; j2++) {
                    int d = j2 * 16 + l16;
                    float2 cs = tab[srel * 32 + d];
                    float x1 = acc[i][j2][r] * qs;
                    float x2 = acc[i][j2 + 2][r] * qs;
                    strip[(quad * 4 + r) * 72 + d]      = f2bf(x1 * cs.x - x2 * cs.y);
                    strip[(quad * 4 + r) * 72 + d + 32] = f2bf(x2 * cs.x + x1 * cs.y);
                }
            }
            // readback row-major (same wave: lgkmcnt orders RAW) + coalesced store
            // TWO passes: each covers 32 of the 64 cols (c*32 + quad*8 + 0..7)
            if (z == 0) {
                u16* row = Qp + ((size_t)(b * 16 + h) * 2048 + srel0 + l16) * 64;
                for (int c = 0; c < 2; c++) {
                    short8 vv = *reinterpret_cast<const short8*>(
                        &strip[l16 * 72 + c * 32 + quad * 8]);
                    *reinterpret_cast<short8*>(&row[c * 32 + quad * 8]) = vv;
                }
            } else {
                int t = srel0 >> 4;
                u16* Kbh = Kf + (size_t)(b * 16 + h) * 131072;
                for (int kk = 0; kk < 2; kk++) {
                    short8 vv = *reinterpret_cast<const short8*>(
                        &strip[l16 * 72 + kk * 32 + quad * 8]);
                    *reinterpret_cast<short8*>(&Kbh[(size_t)(t * 2 + kk) * 512 + lane * 8]) = vv;
                }
            }
        }
    }
}

// ---------------- plain GEMM (output projection): C = A @ Bt^T, fp32 out -----
__global__ __launch_bounds__(256) void gemm_bt_f32(const u16* __restrict__ A,
                                                   const u16* __restrict__ Bt,
                                                   float* __restrict__ C,
                                                   int M, int N, int K) {
    int m0 = blockIdx.y * 128, n0 = blockIdx.x * 128;
    __shared__ u16 As[128 * 32];
    __shared__ u16 Bs[128 * 32];
    int tid = threadIdx.x;
    int wave = tid >> 6, lane = tid & 63, quad = lane >> 4, l16 = lane & 15;
    int wm = (wave >> 1) * 64, wn = (wave & 1) * 64;
    f32x4 acc[4][4];
    for (int i = 0; i < 4; i++)
        for (int j = 0; j < 4; j++)
            for (int r = 0; r < 4; r++) acc[i][j][r] = 0.f;

    for (int k0 = 0; k0 < K; k0 += 32) {
        __syncthreads();
        for (int c = 0; c < 2; c++) {
            int e = (tid + c * 256) * 8;
            int row = e >> 5, col = e & 31;
            gload16(&A[(size_t)(m0 + row) * K + k0 + col], &As[e]);
            gload16(&Bt[(size_t)(n0 + row) * K + k0 + col], &Bs[e]);
        }
        __syncthreads();
        short8 af[4], bfr[4];
        for (int i = 0; i < 4; i++)
            af[i] = *reinterpret_cast<const short8*>(&As[(wm + i * 16 + l16) * 32 + quad * 8]);
        for (int j = 0; j < 4; j++)
            bfr[j] = *reinterpret_cast<const short8*>(&Bs[(wn + j * 16 + l16) * 32 + quad * 8]);
        for (int i = 0; i < 4; i++)
            for (int j = 0; j < 4; j++)
                acc[i][j] = MFMA16(af[i], bfr[j], acc[i][j]);
    }

    for (int i = 0; i < 4; i++)
        for (int r = 0; r < 4; r++) {
            int m = m0 + wm + i * 16 + quad * 4 + r;
            for (int j = 0; j < 4; j++)
                C[(size_t)m * N + n0 + wn + j * 16 + l16] = acc[i][j][r];
        }
}

// ---------------- flash attention (barrier-free, lean-VALU K-loop) -----------
// Grid (32 bh, 16 q-tiles), 8 waves: qg=wave&3 (32 q-rows, groups g=0,1),
// kh=wave>>2 (kv half of 128 tile). K/V frags: coalesced dwordx4 from global
// (fragment order, L2-resident). LDS only for per-wave P strips -> no barrier
// in the loop. Softmax denominators via ones-MFMA on the SAME bf16 P as the
// numerator (consistent ratio, zero VALU adds). exp2 (log2e folded into Q).
__global__ __launch_bounds__(512, 4) void flash_attn(const u16* __restrict__ Qp,
                                                     const u16* __restrict__ Kf,
                                                     const u16* __restrict__ Vf,
                                                     u16* __restrict__ attn) {
    int bh = blockIdx.x, q0 = blockIdx.y * 128;
    const u16* Q = Qp + (size_t)bh * 131072;
    __shared__ u16 smem[8 * 32 * 76];   // per-wave P strips (38912 B)
    int tid = threadIdx.x, wave = tid >> 6, lane = tid & 63;
    int quad = lane >> 4, l16 = lane & 15;
    int qg = wave & 3, kh = wave >> 2;
    u16* Pw = smem + wave * (32 * 76);

    // running fragment pointers (uniform per-iter increments -> scalar adds)
    const u16* kp  = Kf + (size_t)bh * 131072 + kh * 4096 + lane * 8;
    const u16* kp2 = kp + 2048;    // nt = 2,3 (keeps imm offsets < 4096 B)
    const u16* vp  = Vf + (size_t)bh * 131072 + kh * 4096 + lane * 8;
    const u16* vp2 = vp + 2048;    // kk = 1

    short8 qf[2][2];   // B-frag: Q[q0+qg*32+g*16+l16][kk*32+quad*8 .. +7]
    for (int g = 0; g < 2; g++)
        for (int kk = 0; kk < 2; kk++)
            qf[g][kk] = *reinterpret_cast<const short8*>(
                &Q[(size_t)(q0 + qg * 32 + g * 16 + l16) * 64 + kk * 32 + quad * 8]);

    const f32x4 z4 = {0.f, 0.f, 0.f, 0.f};
    short8 ones;
    for (int j = 0; j < 8; j++) ones[j] = (short)0x3F80;   // bf16 1.0

    f32x4 Oacc[2][4], Osum[2];
    for (int g = 0; g < 2; g++) {
        for (int dt = 0; dt < 4; dt++)
            for (int r = 0; r < 4; r++) Oacc[g][dt][r] = 0.f;
        for (int r = 0; r < 4; r++) Osum[g][r] = 0.f;
    }

    for (int it = 0; it < 16; it++) {
        // S^T = K Q^T (zero-C chained: no per-iter accumulator zeroing)
        f32x4 st[2][4];
        for (int nt = 0; nt < 4; nt++) {
            const u16* kb = (nt < 2) ? kp : kp2;
            int off = (nt & 1) * 1024;
            short8 af0 = *reinterpret_cast<const short8*>(kb + off);
            short8 af1 = *reinterpret_cast<const short8*>(kb + off + 512);
            st[0][nt] = MFMA16(af0, qf[0][0], z4);
            st[0][nt] = MFMA16(af1, qf[0][1], st[0][nt]);
            st[1][nt] = MFMA16(af0, qf[1][0], z4);
            st[1][nt] = MFMA16(af1, qf[1][1], st[1][nt]);
        }

        // p = exp2(st); packed bf16 -> per-wave LDS strip (b64 stores)
        for (int g = 0; g < 2; g++)
            for (int nt = 0; nt < 4; nt++) {
                uint2 w;
                w.x = pk2(exp2f(st[g][nt][0]), exp2f(st[g][nt][1]));
                w.y = pk2(exp2f(st[g][nt][2]), exp2f(st[g][nt][3]));
                *reinterpret_cast<uint2*>(
                    &Pw[(g * 16 + l16) * 76 + nt * 16 + quad * 4]) = w;
            }
        // same-wave RAW on Pw -> lgkmcnt; NO barrier

        // O += P V ; denom += P * ones (same bf16 P -> consistent softmax)
        for (int kk = 0; kk < 2; kk++) {
            const u16* vb = kk ? vp2 : vp;
            short8 pa0 = *reinterpret_cast<const short8*>(
                &Pw[l16 * 76 + kk * 32 + quad * 8]);
            short8 pa1 = *reinterpret_cast<const short8*>(
                &Pw[(16 + l16) * 76 + kk * 32 + quad * 8]);
            for (int dt = 0; dt < 4; dt++) {
                short8 bv = *reinterpret_cast<const short8*>(vb + dt * 512);
                Oacc[0][dt] = MFMA16(pa0, bv, Oacc[0][dt]);
                Oacc[1][dt] = MFMA16(pa1, bv, Oacc[1][dt]);
            }
            Osum[0] = MFMA16(pa0, ones, Osum[0]);
            Osum[1] = MFMA16(pa1, ones, Osum[1]);
        }
        kp += 8192; kp2 += 8192; vp += 8192; vp2 += 8192;
    }

    // cross-half reduction through LDS (overlay on P strips; 2 barriers total)
    // Osum[g][r] = denom of q-row qg*32+g*16+quad*4+r (same across l16)
    float* Of = reinterpret_cast<float*>(smem);        // [128][65] padded
    float* ph = Of + 128 * 65;                         // [128] half-denoms
    __syncthreads();
    if (kh == 1) {
        for (int g = 0; g < 2; g++) {
            for (int dt = 0; dt < 4; dt++)
                for (int r = 0; r < 4; r++)
                    Of[(qg * 32 + g * 16 + quad * 4 + r) * 65 + dt * 16 + l16] = Oacc[g][dt][r];
            if (l16 == 0)
                for (int r = 0; r < 4; r++)
                    ph[qg * 32 + g * 16 + quad * 4 + r] = Osum[g][r];
        }
    }
    __syncthreads();
    if (kh == 0) {
        int b = bh >> 4, h = bh & 15;
        for (int g = 0; g < 2; g++) {
            float linv[4];
            for (int r = 0; r < 4; r++)
                linv[r] = 1.f / (Osum[g][r] + ph[qg * 32 + g * 16 + quad * 4 + r]);
            for (int dt = 0; dt < 4; dt++)
                for (int r = 0; r < 4; r++) {
                    float o = Oacc[g][dt][r] +
                              Of[(qg * 32 + g * 16 + quad * 4 + r) * 65 + dt * 16 + l16];
                    int s = q0 + qg * 32 + g * 16 + quad * 4 + r;
                    attn[((size_t)(b * 2048 + s)) * 1024 + h * 64 + dt * 16 + l16] =
                        f2bf(o * linv[r]);
                }
        }
    }
}

// ---------------- launcher ----------------------------------------------------
extern "C" void kernel_launch(void* const* d_in, const int* in_sizes, int n_in,
                              void* d_out, int out_size, void* d_ws, size_t ws_size,
                              hipStream_t stream) {
    const float* q  = (const float*)d_in[0];
    const float* k  = (const float*)d_in[1];
    const float* v  = (const float*)d_in[2];
    const float* wq = (const float*)d_in[3];
    const float* wk = (const float*)d_in[4];
    const float* wv = (const float*)d_in[5];
    const float* wo = (const float*)d_in[6];

    u16* ws = (u16*)d_ws;
    u16* WT  = ws;                        // 4 * 1048576 u16 (W^T bf16)
    u16* X3  = ws + (size_t)4 * 1048576;  // 3 * 4194304 u16 (bf16 inputs)
    u16* QKV = X3 + (size_t)3 * 4194304;  // 3 * 4194304 u16
    u16* Qp  = QKV;                       // [32][2048][64] rope'd, *0.125*log2e
    u16* Kf  = QKV + (size_t)1 * 4194304; // fragment-ordered rope'd K
    u16* Vf  = QKV + (size_t)2 * 4194304; // fragment-ordered V
    // region reuse (stream-ordered): X3 dead after gemm_qkv
    u16* attn = X3;                       // [B,S,E] bf16 flash output
    // d_out doubles as scratch for the rope table until gemm_bt_f32 overwrites it
    float2* tab = (float2*)d_out;         // [2048][32] cos/sin

    prep<<<16640, 256, 0, stream>>>(q, k, v, wq, wk, wv, wo, X3, WT, tab);
    gemm_qkv<<<dim3(8, 32, 3), 256, 0, stream>>>(X3, WT, Qp, Kf, Vf, tab);
    flash_attn<<<dim3(32, 16), 512, 0, stream>>>(Qp, Kf, Vf, attn);
    gemm_bt_f32<<<dim3(8, 32, 1), 256, 0, stream>>>(
        attn, WT + (size_t)3 * 1048576, (float*)d_out, 4096, 1024, 1024);
}

// Round 9
// 235.874 us; speedup vs baseline: 1.0493x; 1.0493x over previous
//
#include <hip/hip_runtime.h>
#include <hip/hip_bf16.h>

// RotaryMultiHeadAttention on MI355X (gfx950)
// B=2, S=2048, E=1024, H=16, Dh=64
//
// Pipeline (4 launches):
//   prep:        conv_x + transpose_w + rope_table fused (flat grid, 3 ranges)
//   gemm_qkv:    fused proj + RoPE; K,V in MFMA-fragment order; coalesced
//                epilogue via per-wave LDS strips
//   flash_attn:  barrier-free K-loop, raw v_exp_f32 softmax, psum-via-ones-MFMA
//   gemm_bt_f32: d_out = attn @ Wo^T fp32 (overwrites rope table)

typedef unsigned short u16;
typedef unsigned int u32;
typedef __attribute__((ext_vector_type(8))) short short8;   // 8 bf16 (4 VGPRs)
typedef __attribute__((ext_vector_type(4))) float f32x4;    // MFMA C/D

#define MFMA16(a, b, c) __builtin_amdgcn_mfma_f32_16x16x32_bf16((a), (b), (c), 0, 0, 0)

typedef __attribute__((address_space(3))) u16 lds_u16;
typedef __attribute__((address_space(1))) const u16 glb_u16;

#define QSCALE 0.18033688011f   // 0.125 * log2(e): flash args are exp2-domain

// raw v_exp_f32 (2^x) — 1 instruction; exp2f() libm lowers to ~20-op precise
// OCML path (R8 regression: VALUBusy 43->55%)
#define FEXP2(x) __builtin_amdgcn_exp2f(x)

__device__ __forceinline__ void gload16(const u16* g, u16* l) {
    __builtin_amdgcn_global_load_lds((glb_u16*)g, (lds_u16*)l, 16, 0, 0);
}

__device__ __forceinline__ u16 f2bf(float f) {
    __hip_bfloat16 h = __float2bfloat16(f);
    return *reinterpret_cast<u16*>(&h);
}

// pack two fp32 -> two bf16 (round-half-up; ±1/2 ulp vs RNE, fine for P)
__device__ __forceinline__ u32 pk2(float a, float b) {
    u32 ua = __float_as_uint(a) + 0x8000u;
    u32 ub = __float_as_uint(b) + 0x8000u;
    return (ua >> 16) | (ub & 0xffff0000u);
}

// ---------------- fused prep: conv_x | transpose_w | rope_table --------------
__global__ __launch_bounds__(256) void prep(const float* __restrict__ q,
                                            const float* __restrict__ k,
                                            const float* __restrict__ v,
                                            const float* __restrict__ w0,
                                            const float* __restrict__ w1,
                                            const float* __restrict__ w2,
                                            const float* __restrict__ w3,
                                            u16* __restrict__ X3,
                                            u16* __restrict__ WT,
                                            float2* __restrict__ tab) {
    __shared__ float t[32][33];
    int blk = blockIdx.x, tid = threadIdx.x;
    if (blk < 12288) {
        // fp32 -> bf16 conversion of q/k/v
        int z = blk >> 12, xb = blk & 4095;
        const float* src = (z == 0) ? q : (z == 1) ? k : v;
        int i = (xb * 256 + tid) * 4;
        float4 f = *reinterpret_cast<const float4*>(src + i);
        ushort4 o;
        o.x = f2bf(f.x); o.y = f2bf(f.y); o.z = f2bf(f.z); o.w = f2bf(f.w);
        *reinterpret_cast<ushort4*>(X3 + (size_t)z * 4194304 + i) = o;
    } else if (blk < 16384) {
        // weight transpose + bf16: WT[z][n][k] = W[k][n]
        int idx = blk - 12288;
        int zc = idx & 3;
        int n0 = ((idx >> 2) & 31) * 32, k0 = (idx >> 7) * 32;
        const float* Ws[4] = {w0, w1, w2, w3};
        const float* W = Ws[zc];
        int tx = tid & 31, ty = tid >> 5;
        for (int r = 0; r < 4; r++)
            t[ty + r * 8][tx] = W[(k0 + ty + r * 8) * 1024 + n0 + tx];
        __syncthreads();
        u16* out = WT + (size_t)zc * 1048576;
        for (int r = 0; r < 4; r++)
            out[(n0 + ty + r * 8) * 1024 + k0 + tx] = f2bf(t[tx][ty + r * 8]);
    } else {
        // rope table: tab[s][d] = (cos, sin)(s * 10000^(-d/32))
        int gid = (blk - 16384) * 256 + tid;
        int s = gid >> 5, d = gid & 31;
        float inv = powf(10000.f, -(float)d / 32.f);  // accurate; phase matters at s~2048
        float fr = (float)s * inv;
        tab[gid] = make_float2(cosf(fr), sinf(fr));
    }
}

// ---------------- fused QKV GEMM + RoPE + fragment-order pack ----------------
// Kf element (bh, srel, d): t=srel>>4, lf=srel&15, kk=d>>5, qd=(d>>3)&3, j=d&7
//   addr = bh*131072 + ((t*2+kk)*4+qd)*128 + lf*8 + j
// Vf element (bh, srel, d): u=srel>>5, qv=(srel>>3)&3, j0=srel&7, dt=d>>4, lf=d&15
//   addr = bh*131072 + ((u*4+dt)*4+qv)*128 + lf*8 + j0
// Q/K epilogue: rope in registers -> per-wave LDS strip [16][72] -> coalesced
// 16B/lane stores; TWO readback passes cover all 64 cols (R7 bug fixed in R8).
__global__ __launch_bounds__(256) void gemm_qkv(const u16* __restrict__ Aall,
                                                const u16* __restrict__ WT,
                                                u16* __restrict__ Qp,
                                                u16* __restrict__ Kf,
                                                u16* __restrict__ Vf,
                                                const float2* __restrict__ tab) {
    int z = blockIdx.z;
    const u16* A  = Aall + (size_t)z * 4194304;
    const u16* Bt = WT + (size_t)z * 1048576;
    const int K = 1024;
    int m0 = blockIdx.y * 128, n0 = blockIdx.x * 128;
    __shared__ u16 smem[9216];   // As[4096] | Bs[4096]; epilogue strips reuse (4x2304)
    u16* As = smem;
    u16* Bs = smem + 4096;
    int tid = threadIdx.x;
    int wave = tid >> 6, lane = tid & 63, quad = lane >> 4, l16 = lane & 15;
    int wm = (wave >> 1) * 64, wn = (wave & 1) * 64;
    f32x4 acc[4][4];
    for (int i = 0; i < 4; i++)
        for (int j = 0; j < 4; j++)
            for (int r = 0; r < 4; r++) acc[i][j][r] = 0.f;

    for (int k0 = 0; k0 < K; k0 += 32) {
        __syncthreads();
        for (int c = 0; c < 2; c++) {
            int e = (tid + c * 256) * 8;
            int row = e >> 5, col = e & 31;
            gload16(&A[(size_t)(m0 + row) * K + k0 + col], &As[e]);
            gload16(&Bt[(size_t)(n0 + row) * K + k0 + col], &Bs[e]);
        }
        __syncthreads();
        short8 af[4], bfr[4];
        for (int i = 0; i < 4; i++)
            af[i] = *reinterpret_cast<const short8*>(&As[(wm + i * 16 + l16) * 32 + quad * 8]);
        for (int j = 0; j < 4; j++)
            bfr[j] = *reinterpret_cast<const short8*>(&Bs[(wn + j * 16 + l16) * 32 + quad * 8]);
        for (int i = 0; i < 4; i++)
            for (int j = 0; j < 4; j++)
                acc[i][j] = MFMA16(af[i], bfr[j], acc[i][j]);
    }

    int h = (n0 + wn) >> 6;                  // head index of this wave's 64-col strip
    if (z == 2) {
        // V -> fragment order, r-packed ushort4 stores (no LDS use)
        for (int i = 0; i < 4; i++) {
            int sbase = m0 + wm + i * 16 + quad * 4;
            int b = sbase >> 11, srel = sbase & 2047;
            int u = srel >> 5, qv = (srel >> 3) & 3, j0 = srel & 7;
            u16* Vbh = Vf + ((size_t)(b * 16 + h)) * 131072;
            for (int j = 0; j < 4; j++) {
                ushort4 o;
                o.x = f2bf(acc[i][j][0]);
                o.y = f2bf(acc[i][j][1]);
                o.z = f2bf(acc[i][j][2]);
                o.w = f2bf(acc[i][j][3]);
                *reinterpret_cast<ushort4*>(
                    &Vbh[(size_t)(((u * 4 + j) * 4 + qv) * 128 + l16 * 8 + j0)]) = o;
            }
        }
    } else {
        __syncthreads();                       // done reading As/Bs
        u16* strip = smem + wave * 2304;       // per-wave [16][72]
        const float qs = (z == 0) ? QSCALE : 1.f;
        for (int i = 0; i < 4; i++) {
            int mb = m0 + wm + i * 16;
            int b = mb >> 11, srel0 = mb & 2047;
            // rope in registers, write rotated rows into strip (C-layout order)
            for (int r = 0; r < 4; r++) {
                int srel = srel0 + quad * 4 + r;
                for (int j2 = 0; j2 < 2; j2++) {
                    int d = j2 * 16 + l16;
                    float2 cs = tab[srel * 32 + d];
                    float x1 = acc[i][j2][r] * qs;
                    float x2 = acc[i][j2 + 2][r] * qs;
                    strip[(quad * 4 + r) * 72 + d]      = f2bf(x1 * cs.x - x2 * cs.y);
                    strip[(quad * 4 + r) * 72 + d + 32] = f2bf(x2 * cs.x + x1 * cs.y);
                }
            }
            // readback row-major (same wave: lgkmcnt orders RAW) + coalesced store
            if (z == 0) {
                u16* row = Qp + ((size_t)(b * 16 + h) * 2048 + srel0 + l16) * 64;
                for (int c = 0; c < 2; c++) {
                    short8 vv = *reinterpret_cast<const short8*>(
                        &strip[l16 * 72 + c * 32 + quad * 8]);
                    *reinterpret_cast<short8*>(&row[c * 32 + quad * 8]) = vv;
                }
            } else {
                int t = srel0 >> 4;
                u16* Kbh = Kf + (size_t)(b * 16 + h) * 131072;
                for (int kk = 0; kk < 2; kk++) {
                    short8 vv = *reinterpret_cast<const short8*>(
                        &strip[l16 * 72 + kk * 32 + quad * 8]);
                    *reinterpret_cast<short8*>(&Kbh[(size_t)(t * 2 + kk) * 512 + lane * 8]) = vv;
                }
            }
        }
    }
}

// ---------------- plain GEMM (output projection): C = A @ Bt^T, fp32 out -----
__global__ __launch_bounds__(256) void gemm_bt_f32(const u16* __restrict__ A,
                                                   const u16* __restrict__ Bt,
                                                   float* __restrict__ C,
                                                   int M, int N, int K) {
    int m0 = blockIdx.y * 128, n0 = blockIdx.x * 128;
    __shared__ u16 As[128 * 32];
    __shared__ u16 Bs[128 * 32];
    int tid = threadIdx.x;
    int wave = tid >> 6, lane = tid & 63, quad = lane >> 4, l16 = lane & 15;
    int wm = (wave >> 1) * 64, wn = (wave & 1) * 64;
    f32x4 acc[4][4];
    for (int i = 0; i < 4; i++)
        for (int j = 0; j < 4; j++)
            for (int r = 0; r < 4; r++) acc[i][j][r] = 0.f;

    for (int k0 = 0; k0 < K; k0 += 32) {
        __syncthreads();
        for (int c = 0; c < 2; c++) {
            int e = (tid + c * 256) * 8;
            int row = e >> 5, col = e & 31;
            gload16(&A[(size_t)(m0 + row) * K + k0 + col], &As[e]);
            gload16(&Bt[(size_t)(n0 + row) * K + k0 + col], &Bs[e]);
        }
        __syncthreads();
        short8 af[4], bfr[4];
        for (int i = 0; i < 4; i++)
            af[i] = *reinterpret_cast<const short8*>(&As[(wm + i * 16 + l16) * 32 + quad * 8]);
        for (int j = 0; j < 4; j++)
            bfr[j] = *reinterpret_cast<const short8*>(&Bs[(wn + j * 16 + l16) * 32 + quad * 8]);
        for (int i = 0; i < 4; i++)
            for (int j = 0; j < 4; j++)
                acc[i][j] = MFMA16(af[i], bfr[j], acc[i][j]);
    }

    for (int i = 0; i < 4; i++)
        for (int r = 0; r < 4; r++) {
            int m = m0 + wm + i * 16 + quad * 4 + r;
            for (int j = 0; j < 4; j++)
                C[(size_t)m * N + n0 + wn + j * 16 + l16] = acc[i][j][r];
        }
}

// ---------------- flash attention (barrier-free, lean-VALU K-loop) -----------
// Grid (32 bh, 16 q-tiles), 8 waves: qg=wave&3 (32 q-rows, groups g=0,1),
// kh=wave>>2 (kv half of 128 tile). K/V frags: coalesced dwordx4 from global
// (fragment order, L2-resident). LDS only for per-wave P strips -> no barrier
// in the loop. Softmax denominators via ones-MFMA on the SAME bf16 P as the
// numerator. exp2 domain (log2e folded into Q), raw v_exp_f32.
__global__ __launch_bounds__(512, 4) void flash_attn(const u16* __restrict__ Qp,
                                                     const u16* __restrict__ Kf,
                                                     const u16* __restrict__ Vf,
                                                     u16* __restrict__ attn) {
    int bh = blockIdx.x, q0 = blockIdx.y * 128;
    const u16* Q = Qp + (size_t)bh * 131072;
    __shared__ u16 smem[8 * 32 * 76];   // per-wave P strips (38912 B)
    int tid = threadIdx.x, wave = tid >> 6, lane = tid & 63;
    int quad = lane >> 4, l16 = lane & 15;
    int qg = wave & 3, kh = wave >> 2;
    u16* Pw = smem + wave * (32 * 76);

    // running fragment pointers (uniform per-iter increments -> scalar adds)
    const u16* kp  = Kf + (size_t)bh * 131072 + kh * 4096 + lane * 8;
    const u16* kp2 = kp + 2048;    // nt = 2,3 (keeps imm offsets < 4096 B)
    const u16* vp  = Vf + (size_t)bh * 131072 + kh * 4096 + lane * 8;
    const u16* vp2 = vp + 2048;    // kk = 1

    short8 qf[2][2];   // B-frag: Q[q0+qg*32+g*16+l16][kk*32+quad*8 .. +7]
    for (int g = 0; g < 2; g++)
        for (int kk = 0; kk < 2; kk++)
            qf[g][kk] = *reinterpret_cast<const short8*>(
                &Q[(size_t)(q0 + qg * 32 + g * 16 + l16) * 64 + kk * 32 + quad * 8]);

    const f32x4 z4 = {0.f, 0.f, 0.f, 0.f};
    short8 ones;
    for (int j = 0; j < 8; j++) ones[j] = (short)0x3F80;   // bf16 1.0

    f32x4 Oacc[2][4], Osum[2];
    for (int g = 0; g < 2; g++) {
        for (int dt = 0; dt < 4; dt++)
            for (int r = 0; r < 4; r++) Oacc[g][dt][r] = 0.f;
        for (int r = 0; r < 4; r++) Osum[g][r] = 0.f;
    }

    for (int it = 0; it < 16; it++) {
        // S^T = K Q^T (zero-C chained: no per-iter accumulator zeroing)
        f32x4 st[2][4];
        for (int nt = 0; nt < 4; nt++) {
            const u16* kb = (nt < 2) ? kp : kp2;
            int off = (nt & 1) * 1024;
            short8 af0 = *reinterpret_cast<const short8*>(kb + off);
            short8 af1 = *reinterpret_cast<const short8*>(kb + off + 512);
            st[0][nt] = MFMA16(af0, qf[0][0], z4);
            st[0][nt] = MFMA16(af1, qf[0][1], st[0][nt]);
            st[1][nt] = MFMA16(af0, qf[1][0], z4);
            st[1][nt] = MFMA16(af1, qf[1][1], st[1][nt]);
        }

        // p = 2^st (one v_exp_f32 each); packed bf16 -> per-wave LDS strip
        for (int g = 0; g < 2; g++)
            for (int nt = 0; nt < 4; nt++) {
                uint2 w;
                w.x = pk2(FEXP2(st[g][nt][0]), FEXP2(st[g][nt][1]));
                w.y = pk2(FEXP2(st[g][nt][2]), FEXP2(st[g][nt][3]));
                *reinterpret_cast<uint2*>(
                    &Pw[(g * 16 + l16) * 76 + nt * 16 + quad * 4]) = w;
            }
        // same-wave RAW on Pw -> lgkmcnt; NO barrier

        // O += P V ; denom += P * ones (same bf16 P -> consistent softmax)
        for (int kk = 0; kk < 2; kk++) {
            const u16* vb = kk ? vp2 : vp;
            short8 pa0 = *reinterpret_cast<const short8*>(
                &Pw[l16 * 76 + kk * 32 + quad * 8]);
            short8 pa1 = *reinterpret_cast<const short8*>(
                &Pw[(16 + l16) * 76 + kk * 32 + quad * 8]);
            for (int dt = 0; dt < 4; dt++) {
                short8 bv = *reinterpret_cast<const short8*>(vb + dt * 512);
                Oacc[0][dt] = MFMA16(pa0, bv, Oacc[0][dt]);
                Oacc[1][dt] = MFMA16(pa1, bv, Oacc[1][dt]);
            }
            Osum[0] = MFMA16(pa0, ones, Osum[0]);
            Osum[1] = MFMA16(pa1, ones, Osum[1]);
        }
        kp += 8192; kp2 += 8192; vp += 8192; vp2 += 8192;
    }

    // cross-half reduction through LDS (overlay on P strips; 2 barriers total)
    // Osum[g][r] = denom of q-row qg*32+g*16+quad*4+r (same across l16)
    float* Of = reinterpret_cast<float*>(smem);        // [128][65] padded
    float* ph = Of + 128 * 65;                         // [128] half-denoms
    __syncthreads();
    if (kh == 1) {
        for (int g = 0; g < 2; g++) {
            for (int dt = 0; dt < 4; dt++)
                for (int r = 0; r < 4; r++)
                    Of[(qg * 32 + g * 16 + quad * 4 + r) * 65 + dt * 16 + l16] = Oacc[g][dt][r];
            if (l16 == 0)
                for (int r = 0; r < 4; r++)
                    ph[qg * 32 + g * 16 + quad * 4 + r] = Osum[g][r];
        }
    }
    __syncthreads();
    if (kh == 0) {
        int b = bh >> 4, h = bh & 15;
        for (int g = 0; g < 2; g++) {
            float linv[4];
            for (int r = 0; r < 4; r++)
                linv[r] = 1.f / (Osum[g][r] + ph[qg * 32 + g * 16 + quad * 4 + r]);
            for (int dt = 0; dt < 4; dt++)
                for (int r = 0; r < 4; r++) {
                    float o = Oacc[g][dt][r] +
                              Of[(qg * 32 + g * 16 + quad * 4 + r) * 65 + dt * 16 + l16];
                    int s = q0 + qg * 32 + g * 16 + quad * 4 + r;
                    attn[((size_t)(b * 2048 + s)) * 1024 + h * 64 + dt * 16 + l16] =
                        f2bf(o * linv[r]);
                }
        }
    }
}

// ---------------- launcher ----------------------------------------------------
extern "C" void kernel_launch(void* const* d_in, const int* in_sizes, int n_in,
                              void* d_out, int out_size, void* d_ws, size_t ws_size,
                              hipStream_t stream) {
    const float* q  = (const float*)d_in[0];
    const float* k  = (const float*)d_in[1];
    const float* v  = (const float*)d_in[2];
    const float* wq = (const float*)d_in[3];
    const float* wk = (const float*)d_in[4];
    const float* wv = (const float*)d_in[5];
    const float* wo = (const float*)d_in[6];

    u16* ws = (u16*)d_ws;
    u16* WT  = ws;                        // 4 * 1048576 u16 (W^T bf16)
    u16* X3  = ws + (size_t)4 * 1048576;  // 3 * 4194304 u16 (bf16 inputs)
    u16* QKV = X3 + (size_t)3 * 4194304;  // 3 * 4194304 u16
    u16* Qp  = QKV;                       // [32][2048][64] rope'd, *0.125*log2e
    u16* Kf  = QKV + (size_t)1 * 4194304; // fragment-ordered rope'd K
    u16* Vf  = QKV + (size_t)2 * 4194304; // fragment-ordered V
    // region reuse (stream-ordered): X3 dead after gemm_qkv
    u16* attn = X3;                       // [B,S,E] bf16 flash output
    // d_out doubles as scratch for the rope table until gemm_bt_f32 overwrites it
    float2* tab = (float2*)d_out;         // [2048][32] cos/sin

    prep<<<16640, 256, 0, stream>>>(q, k, v, wq, wk, wv, wo, X3, WT, tab);
    gemm_qkv<<<dim3(8, 32, 3), 256, 0, stream>>>(X3, WT, Qp, Kf, Vf, tab);
    flash_attn<<<dim3(32, 16), 512, 0, stream>>>(Qp, Kf, Vf, attn);
    gemm_bt_f32<<<dim3(8, 32, 1), 256, 0, stream>>>(
        attn, WT + (size_t)3 * 1048576, (float*)d_out, 4096, 1024, 1024);
}